// Round 10
// baseline (1987.149 us; speedup 1.0000x reference)
//
#include <hip/hip_runtime.h>
#include <math.h>

namespace {

constexpr int NN = 100000;
constexpr int NE = 1600000;
constexpr float EPS = 1e-5f;

// leaky(x) == max(x, 0.01x) for all x (2 instr: v_mul + v_max)
__device__ __forceinline__ float leaky(float x) { return fmaxf(x, 0.01f * x); }
__device__ __forceinline__ float ffma(float a, float b, float c) { return __builtin_fmaf(a, b, c); }

// ---------------- preprocessing: degrees, dinv, CSR-by-dst, degree-sort ----------------

__global__ __launch_bounds__(256) void k_init(int* __restrict__ deg, int* __restrict__ counter,
                                              int* __restrict__ bins, int n) {
  int i = blockIdx.x * 256 + threadIdx.x;
  if (i < n) deg[i] = 1;          // self-loop
  if (i == 0) counter[0] = 0;
  if (blockIdx.x == 0 && threadIdx.x < 256) bins[threadIdx.x] = 0;
}

__global__ __launch_bounds__(256) void k_count(const int* __restrict__ dst, int* __restrict__ deg, int e) {
  int i = blockIdx.x * 256 + threadIdx.x;
  if (i < e) atomicAdd(&deg[dst[i]], 1);
}

// dinv = rsqrt(deg); allocate CSR slot ranges via wave-aggregated atomic
__global__ __launch_bounds__(256) void k_alloc(const int* __restrict__ deg, float* __restrict__ dinv,
                                               int* __restrict__ offsets, int* __restrict__ cursor,
                                               int* __restrict__ counter, int n) {
  int i = blockIdx.x * 256 + threadIdx.x;
  int lane = threadIdx.x & 63;
  int c = 0;
  if (i < n) {
    int d = deg[i];
    dinv[i] = rsqrtf((float)d);
    c = d - 1;                    // real in-edges only (self-loop handled analytically)
  }
  // wave inclusive scan
  int v = c;
#pragma unroll
  for (int s = 1; s < 64; s <<= 1) {
    int t = __shfl_up(v, s, 64);
    if (lane >= s) v += t;
  }
  int total = __shfl(v, 63, 64);
  int base = 0;
  if (lane == 63) base = atomicAdd(counter, total);
  base = __shfl(base, 63, 64);
  if (i < n) {
    int off = base + v - c;       // exclusive prefix
    offsets[i] = off;
    cursor[i] = off;
  }
}

// adj entry = (src, norm) fused in one int2 -> single 8B load per edge in k_agg
__global__ __launch_bounds__(256) void k_fill(const int* __restrict__ src, const int* __restrict__ dst,
                                              const float* __restrict__ dinv, int* __restrict__ cursor,
                                              int2* __restrict__ adj, int e) {
  int i = blockIdx.x * 256 + threadIdx.x;
  if (i < e) {
    int s = src[i], d = dst[i];
    int p = atomicAdd(&cursor[d], 1);
    adj[p] = make_int2(s, __float_as_int(dinv[s] * dinv[d]));
  }
}

// degree-sort: histogram -> exclusive scan -> scatter. Nodes grouped by degree so the
// edge loop in k_agg has uniform trip count within a wave (kills exec-mask divergence).
// Per-node math/order unchanged -> bit-identical results.
__global__ __launch_bounds__(256) void k_hist(const int* __restrict__ deg, int* __restrict__ bins, int n) {
  int i = blockIdx.x * 256 + threadIdx.x;
  if (i < n) atomicAdd(&bins[min(deg[i], 255)], 1);
}

__global__ __launch_bounds__(256) void k_scan(const int* __restrict__ bins, int* __restrict__ binpos) {
  __shared__ int tmp[256];
  int t = threadIdx.x;
  tmp[t] = bins[t];
  __syncthreads();
  int acc = 0;
  for (int i = 0; i < t; i++) acc += tmp[i];   // 256 threads x <=255 LDS reads: ~1-2 us
  binpos[t] = acc;
}

__global__ __launch_bounds__(256) void k_scatter(const int* __restrict__ deg, int* __restrict__ binpos,
                                                 int* __restrict__ order, int n) {
  int i = blockIdx.x * 256 + threadIdx.x;
  if (i < n) {
    int p = atomicAdd(&binpos[min(deg[i], 255)], 1);
    order[p] = i;
  }
}

// zero-pad gw1 [94][128] -> [96][128]
__global__ __launch_bounds__(256) void k_padw1(const float* __restrict__ gw1, float* __restrict__ w1p) {
  int i = blockIdx.x * 256 + threadIdx.x;
  if (i < 96 * 128) w1p[i] = (i < 94 * 128) ? gw1[i] : 0.f;
}

// precompute per-layer BN scale/shift: out = acc*scale + shift
// scale = bg*rsqrt(bv+EPS); shift = (gb-bm)*scale + bb   (gb = GCN bias, folded)
struct BNParams {
  const float* bg[5];
  const float* bv[5];
  const float* gb[5];
  const float* bm[5];
  const float* bb[5];
};
__global__ __launch_bounds__(512) void k_bnprep(BNParams p, float* __restrict__ scale, float* __restrict__ shift) {
  int i = threadIdx.x;                    // [0, 400)
  if (i >= 400) return;
  const int ends[5] = {128, 256, 320, 384, 400};
  int l = 0;
  while (i >= ends[l]) l++;
  int c = i - (l ? ends[l - 1] : 0);
  float sc = p.bg[l][c] * rsqrtf(p.bv[l][c] + EPS);
  scale[i] = sc;
  shift[i] = ffma(p.gb[l][c] - p.bm[l][c], sc, p.bb[l][c]);
}

// ---------------- CNN encoder ----------------
// (unchanged — 651 us, VALUBusy 93%, control kernel)
__global__ __launch_bounds__(256, 4) void k_cnn(const float* __restrict__ x,
                                             const float* __restrict__ cw1, const float* __restrict__ cb1,
                                             const float* __restrict__ cw2, const float* __restrict__ cb2,
                                             const float* __restrict__ cw3, const float* __restrict__ cb3,
                                             float* __restrict__ H) {
  __shared__ __align__(16) float inb[2][500];
  __shared__ float c1[2][2940];               // [10 ci][98 h][3 w]
  __shared__ float part[2][2][2][98];         // [node][co-wave][w][h] conv3 partials

  int tid = threadIdx.x;
  int half = tid >> 7;          // node within block (waves 0,1 -> node0; 2,3 -> node1)
  int nt = tid & 127;           // thread id within node
  int lane = tid & 63;
  int node = blockIdx.x * 2 + half;
  int co0 = __builtin_amdgcn_readfirstlane(((tid >> 6) & 1) * 10);  // wave-uniform co-group

  for (int i = tid; i < 2 * 2 * 2 * 98; i += 256) ((float*)part)[i] = 0.f;

  if (nt < 125) {
    const float4* xp = (const float4*)(x + (size_t)node * 500);
    ((float4*)inb[half])[nt] = xp[nt];
  }
  __syncthreads();

  {
    // conv1: one h-row per thread (h = nt, 98 rows), 3 w-outputs x 10 co.
    const float* in = inb[half];
    float* c1p = c1[half];
    int h = nt;
    if (h < 98) {
      float xv[3][5];
#pragma unroll
      for (int kh = 0; kh < 3; kh++)
#pragma unroll
        for (int c = 0; c < 5; c++) xv[kh][c] = in[(h + kh) * 5 + c];
      float* rowp = c1p + h * 3;
#pragma unroll
      for (int co = 0; co < 10; co++) {
        float b = cb1[co];
        float a0 = b, a1 = b, a2 = b;
#pragma unroll
        for (int kh = 0; kh < 3; kh++)
#pragma unroll
          for (int kw = 0; kw < 3; kw++) {
            float wv = cw1[co * 9 + kh * 3 + kw];
            a0 = ffma(xv[kh][kw + 0], wv, a0);
            a1 = ffma(xv[kh][kw + 1], wv, a1);
            a2 = ffma(xv[kh][kw + 2], wv, a2);
          }
        rowp[co * 294 + 0] = leaky(a0);
        rowp[co * 294 + 1] = leaky(a1);
        rowp[co * 294 + 2] = leaky(a2);
      }
    }
  }
  __syncthreads();

  // conv2: lane = hg*2 + w. Each lane: 3 h-rows x 1 w-col x 10 co (wave's co-group).
  int hg = lane >> 1, w = lane & 1;
  int h0 = hg * 3;
  float acc[3][10];
#pragma unroll
  for (int a = 0; a < 3; a++)
#pragma unroll
    for (int c = 0; c < 10; c++) acc[a][c] = 0.f;
  {
    const float* c1p = c1[half];
#pragma unroll 1
    for (int ci = 0; ci < 10; ci++) {
      float r[5][2];
      const float* base = c1p + ci * 294 + h0 * 3 + w;
#pragma unroll
      for (int i = 0; i < 5; i++) {
        r[i][0] = base[i * 3];
        r[i][1] = base[i * 3 + 1];
      }
#pragma unroll
      for (int c = 0; c < 10; c++) {
        const float* wp = cw2 + (co0 + c) * 60 + ci * 6;   // [co][ci][kh][kw]
        float w0 = wp[0], w1 = wp[1], w2v = wp[2], w3v = wp[3], w4 = wp[4], w5 = wp[5];
#pragma unroll
        for (int hh = 0; hh < 3; hh++) {
          float t = acc[hh][c];
          t = ffma(r[hh][0],     w0,  t);
          t = ffma(r[hh][1],     w1,  t);
          t = ffma(r[hh + 1][0], w2v, t);
          t = ffma(r[hh + 1][1], w3v, t);
          t = ffma(r[hh + 2][0], w4,  t);
          t = ffma(r[hh + 2][1], w5,  t);
          acc[hh][c] = t;
        }
      }
    }
#pragma unroll
    for (int c = 0; c < 10; c++) {
      float b = cb2[co0 + c];
#pragma unroll
      for (int hh = 0; hh < 3; hh++) acc[hh][c] = leaky(acc[hh][c] + b);
    }
  }
  __syncthreads();

  // conv3 fused via phased part[] accumulation
  {
    float* pp = &part[half][co0 == 0 ? 0 : 1][w][0];
#pragma unroll
    for (int kh = 0; kh < 3; kh++) {
      float ws[10];
#pragma unroll
      for (int c = 0; c < 10; c++) {
        float wa = cw3[(co0 + c) * 6 + kh * 2 + 0];   // scalar
        float wb = cw3[(co0 + c) * 6 + kh * 2 + 1];   // scalar
        ws[c] = w ? wb : wa;                          // v_cndmask
      }
#pragma unroll
      for (int hh = 0; hh < 3; hh++) {
        float s = 0.f;
#pragma unroll
        for (int c = 0; c < 10; c++) s = ffma(acc[hh][c], ws[c], s);
        pp[h0 + hh - kh + 2] += s;
      }
      __syncthreads();
    }
  }

  {
    float* Hp = H + (size_t)node * 96;
    if (nt < 94) {
      float v = part[half][0][0][nt + 2] + part[half][0][1][nt + 2]
              + part[half][1][0][nt + 2] + part[half][1][1][nt + 2] + cb3[0];
      Hp[nt] = tanhf(v);
    } else if (nt < 96) {
      Hp[nt] = 0.f;
    }
  }
}

// ---------------- GEMM: C[M,FO-tile] = A[M,K] @ W[K,FO] (+ optional BN+tanh epilogue) ----
template <int K, int FO, int BN, bool EPI = false>
__global__ __launch_bounds__(256) void k_gemm(const float* __restrict__ A, const float* __restrict__ W,
                                              float* __restrict__ C, int M,
                                              const float* __restrict__ bns = nullptr,
                                              const float* __restrict__ bnh = nullptr,
                                              int bnofs = 0) {
  __shared__ float As[64][K + 1];
  __shared__ __align__(16) float Ws[K][BN];
  int tid = threadIdx.x;
  int row_base = blockIdx.x * 64;
  int col_base = blockIdx.y * BN;

  for (int idx = tid; idx < 64 * K; idx += 256) {
    int r = idx / K, k = idx - r * K;
    int row = row_base + r;
    As[r][k] = (row < M) ? A[(size_t)row * K + k] : 0.f;
  }
  for (int idx = tid; idx < K * BN; idx += 256) {
    int r = idx / BN, c = idx - r * BN;
    Ws[r][c] = W[r * FO + col_base + c];
  }
  __syncthreads();

  if constexpr (BN == 64) {
    int ty = tid >> 4, tx = tid & 15;
    float acc[4][4] = {};
#pragma unroll 4
    for (int k = 0; k < K; k++) {
      float a0 = As[ty * 4 + 0][k];
      float a1 = As[ty * 4 + 1][k];
      float a2 = As[ty * 4 + 2][k];
      float a3 = As[ty * 4 + 3][k];
      const float4 b = *(const float4*)&Ws[k][tx * 4];
      acc[0][0] = ffma(a0, b.x, acc[0][0]); acc[0][1] = ffma(a0, b.y, acc[0][1]);
      acc[0][2] = ffma(a0, b.z, acc[0][2]); acc[0][3] = ffma(a0, b.w, acc[0][3]);
      acc[1][0] = ffma(a1, b.x, acc[1][0]); acc[1][1] = ffma(a1, b.y, acc[1][1]);
      acc[1][2] = ffma(a1, b.z, acc[1][2]); acc[1][3] = ffma(a1, b.w, acc[1][3]);
      acc[2][0] = ffma(a2, b.x, acc[2][0]); acc[2][1] = ffma(a2, b.y, acc[2][1]);
      acc[2][2] = ffma(a2, b.z, acc[2][2]); acc[2][3] = ffma(a2, b.w, acc[2][3]);
      acc[3][0] = ffma(a3, b.x, acc[3][0]); acc[3][1] = ffma(a3, b.y, acc[3][1]);
      acc[3][2] = ffma(a3, b.z, acc[3][2]); acc[3][3] = ffma(a3, b.w, acc[3][3]);
    }
    float4 s4, h4;
    if constexpr (EPI) {
      s4 = *(const float4*)&bns[bnofs + col_base + tx * 4];
      h4 = *(const float4*)&bnh[bnofs + col_base + tx * 4];
    }
#pragma unroll
    for (int i = 0; i < 4; i++) {
      int row = row_base + ty * 4 + i;
      if (row < M) {
        float4 v;
        if constexpr (EPI) {
          v.x = tanhf(ffma(acc[i][0], s4.x, h4.x));
          v.y = tanhf(ffma(acc[i][1], s4.y, h4.y));
          v.z = tanhf(ffma(acc[i][2], s4.z, h4.z));
          v.w = tanhf(ffma(acc[i][3], s4.w, h4.w));
        } else {
          v = make_float4(acc[i][0], acc[i][1], acc[i][2], acc[i][3]);
        }
        *(float4*)&C[(size_t)row * FO + col_base + tx * 4] = v;
      }
    }
  } else {  // BN == 16: thread = 1 row x 4 cols
    int ty = tid >> 2, tx = tid & 3;
    float acc[4] = {};
#pragma unroll 4
    for (int k = 0; k < K; k++) {
      float a = As[ty][k];
      const float4 b = *(const float4*)&Ws[k][tx * 4];
      acc[0] = ffma(a, b.x, acc[0]); acc[1] = ffma(a, b.y, acc[1]);
      acc[2] = ffma(a, b.z, acc[2]); acc[3] = ffma(a, b.w, acc[3]);
    }
    int row = row_base + ty;
    if (row < M) *(float4*)&C[(size_t)row * FO + col_base + tx * 4] = make_float4(acc[0], acc[1], acc[2], acc[3]);
  }
}

// ---------------- plain aggregation for L1 (FO=96): AH = A_norm @ H ----------------
// 8 lanes/node x 12 cols (3 float4). Degree-sorted node order via order[].
__global__ __launch_bounds__(256) void k_agg96(const float* __restrict__ Hm,
                                               const int* __restrict__ offsets, const int* __restrict__ deg,
                                               const int2* __restrict__ adj,
                                               const float* __restrict__ dinv,
                                               const int* __restrict__ order,
                                               float* __restrict__ out, int n) {
  int tid = threadIdx.x;
  int li = tid >> 3, c12 = (tid & 7) * 12;
  int idx = blockIdx.x * 32 + li;
  if (idx >= n) return;
  int node = order[idx];

  float dv = dinv[node];
  float se = dv * dv;
  const float4* sp = (const float4*)&Hm[(size_t)node * 96 + c12];
  float4 a0 = sp[0], a1 = sp[1], a2 = sp[2];
  a0.x *= se; a0.y *= se; a0.z *= se; a0.w *= se;
  a1.x *= se; a1.y *= se; a1.z *= se; a1.w *= se;
  a2.x *= se; a2.y *= se; a2.z *= se; a2.w *= se;

  const int2* ap = adj + offsets[node];
  int cnt = deg[node] - 1;
  int e = 0;
  for (; e + 1 < cnt; e += 2) {
    int2 e0 = ap[e], e1 = ap[e + 1];
    float n0 = __int_as_float(e0.y), n1 = __int_as_float(e1.y);
    const float4* q0 = (const float4*)&Hm[(size_t)e0.x * 96 + c12];
    const float4* q1 = (const float4*)&Hm[(size_t)e1.x * 96 + c12];
    float4 u0 = q0[0], u1 = q0[1], u2 = q0[2];
    float4 v0 = q1[0], v1 = q1[1], v2 = q1[2];
    a0.x = ffma(u0.x, n0, a0.x); a0.y = ffma(u0.y, n0, a0.y);
    a0.z = ffma(u0.z, n0, a0.z); a0.w = ffma(u0.w, n0, a0.w);
    a1.x = ffma(u1.x, n0, a1.x); a1.y = ffma(u1.y, n0, a1.y);
    a1.z = ffma(u1.z, n0, a1.z); a1.w = ffma(u1.w, n0, a1.w);
    a2.x = ffma(u2.x, n0, a2.x); a2.y = ffma(u2.y, n0, a2.y);
    a2.z = ffma(u2.z, n0, a2.z); a2.w = ffma(u2.w, n0, a2.w);
    a0.x = ffma(v0.x, n1, a0.x); a0.y = ffma(v0.y, n1, a0.y);
    a0.z = ffma(v0.z, n1, a0.z); a0.w = ffma(v0.w, n1, a0.w);
    a1.x = ffma(v1.x, n1, a1.x); a1.y = ffma(v1.y, n1, a1.y);
    a1.z = ffma(v1.z, n1, a1.z); a1.w = ffma(v1.w, n1, a1.w);
    a2.x = ffma(v2.x, n1, a2.x); a2.y = ffma(v2.y, n1, a2.y);
    a2.z = ffma(v2.z, n1, a2.z); a2.w = ffma(v2.w, n1, a2.w);
  }
  if (e < cnt) {
    int2 e0 = ap[e];
    float n0 = __int_as_float(e0.y);
    const float4* q0 = (const float4*)&Hm[(size_t)e0.x * 96 + c12];
    float4 u0 = q0[0], u1 = q0[1], u2 = q0[2];
    a0.x = ffma(u0.x, n0, a0.x); a0.y = ffma(u0.y, n0, a0.y);
    a0.z = ffma(u0.z, n0, a0.z); a0.w = ffma(u0.w, n0, a0.w);
    a1.x = ffma(u1.x, n0, a1.x); a1.y = ffma(u1.y, n0, a1.y);
    a1.z = ffma(u1.z, n0, a1.z); a1.w = ffma(u1.w, n0, a1.w);
    a2.x = ffma(u2.x, n0, a2.x); a2.y = ffma(u2.y, n0, a2.y);
    a2.z = ffma(u2.z, n0, a2.z); a2.w = ffma(u2.w, n0, a2.w);
  }
  float4* op = (float4*)&out[(size_t)node * 96 + c12];
  op[0] = a0; op[1] = a1; op[2] = a2;
}

// ---------------- aggregation + BN (+tanh | +softmax) ----------------
// 8 cols/thread; 1 int2 adj load per edge; edge loop unrolled x4;
// degree-sorted node order (order[]) -> uniform trip count within a wave.
template <int FO, bool SOFT>
__global__ __launch_bounds__(256) void k_agg(const float* __restrict__ XW,
                                             const int* __restrict__ offsets, const int* __restrict__ deg,
                                             const int2* __restrict__ adj,
                                             const float* __restrict__ dinv,
                                             const int* __restrict__ order,
                                             const float* __restrict__ bnscale, const float* __restrict__ bnshift,
                                             int bnofs, float* __restrict__ out, int n) {
  constexpr int TPN = FO / 8;          // threads per node
  constexpr int NPB = 256 / TPN;       // nodes per block
  int tid = threadIdx.x;
  int li = tid / TPN, c8 = (tid % TPN) * 8;
  int idx = blockIdx.x * NPB + li;
  if (idx >= n) return;
  int node = order[idx];

  float dv = dinv[node];
  float se = dv * dv;
  const float4* selfp = (const float4*)&XW[(size_t)node * FO + c8];
  float4 aL = selfp[0], aH = selfp[1];
  aL.x *= se; aL.y *= se; aL.z *= se; aL.w *= se;
  aH.x *= se; aH.y *= se; aH.z *= se; aH.w *= se;

  const int2* ap = adj + offsets[node];
  int cnt = deg[node] - 1;
  int e = 0;
#define EDGE_STEP(AA)                                                        \
  {                                                                          \
    float nm = __int_as_float((AA).y);                                       \
    const float4* q = (const float4*)&XW[(size_t)(AA).x * FO + c8];          \
    float4 v = q[0], w = q[1];                                               \
    aL.x = ffma(v.x, nm, aL.x); aL.y = ffma(v.y, nm, aL.y);                  \
    aL.z = ffma(v.z, nm, aL.z); aL.w = ffma(v.w, nm, aL.w);                  \
    aH.x = ffma(w.x, nm, aH.x); aH.y = ffma(w.y, nm, aH.y);                  \
    aH.z = ffma(w.z, nm, aH.z); aH.w = ffma(w.w, nm, aH.w);                  \
  }
  for (; e + 3 < cnt; e += 4) {
    int2 a0 = ap[e], a1 = ap[e + 1], a2 = ap[e + 2], a3 = ap[e + 3];
    EDGE_STEP(a0); EDGE_STEP(a1); EDGE_STEP(a2); EDGE_STEP(a3);
  }
  for (; e < cnt; e++) {
    int2 a0 = ap[e];
    EDGE_STEP(a0);
  }
#undef EDGE_STEP

  const float4 s4L = *(const float4*)&bnscale[bnofs + c8];
  const float4 s4H = *(const float4*)&bnscale[bnofs + c8 + 4];
  const float4 h4L = *(const float4*)&bnshift[bnofs + c8];
  const float4 h4H = *(const float4*)&bnshift[bnofs + c8 + 4];
  float r[8];
  r[0] = ffma(aL.x, s4L.x, h4L.x); r[1] = ffma(aL.y, s4L.y, h4L.y);
  r[2] = ffma(aL.z, s4L.z, h4L.z); r[3] = ffma(aL.w, s4L.w, h4L.w);
  r[4] = ffma(aH.x, s4H.x, h4H.x); r[5] = ffma(aH.y, s4H.y, h4H.y);
  r[6] = ffma(aH.z, s4H.z, h4H.z); r[7] = ffma(aH.w, s4H.w, h4H.w);

  float4 oL, oH;
  if constexpr (SOFT) {
    float mx = r[0];
#pragma unroll
    for (int i = 1; i < 8; i++) mx = fmaxf(mx, r[i]);
#pragma unroll
    for (int m = TPN / 2; m; m >>= 1) mx = fmaxf(mx, __shfl_xor(mx, m, TPN));
    float sm = 0.f;
#pragma unroll
    for (int i = 0; i < 8; i++) { r[i] = expf(r[i] - mx); sm += r[i]; }
#pragma unroll
    for (int m = TPN / 2; m; m >>= 1) sm += __shfl_xor(sm, m, TPN);
    float inv = 1.f / sm;
#pragma unroll
    for (int i = 0; i < 8; i++) r[i] *= inv;
  } else {
#pragma unroll
    for (int i = 0; i < 8; i++) r[i] = tanhf(r[i]);
  }
  oL = make_float4(r[0], r[1], r[2], r[3]);
  oH = make_float4(r[4], r[5], r[6], r[7]);
  float4* op = (float4*)&out[(size_t)node * FO + c8];
  op[0] = oL;
  op[1] = oH;
}

}  // namespace

extern "C" void kernel_launch(void* const* d_in, const int* in_sizes, int n_in,
                              void* d_out, int out_size, void* d_ws, size_t ws_size,
                              hipStream_t stream) {
  const float* x   = (const float*)d_in[0];
  const int*   ei  = (const int*)d_in[1];
  const float* cw1 = (const float*)d_in[2];
  const float* cb1 = (const float*)d_in[3];
  const float* cw2 = (const float*)d_in[4];
  const float* cb2 = (const float*)d_in[5];
  const float* cw3 = (const float*)d_in[6];
  const float* cb3 = (const float*)d_in[7];
  const float *gw[5], *gb[5], *bng[5], *bnb[5], *bnm[5], *bnv[5];
  for (int l = 0; l < 5; l++) {
    gw[l]  = (const float*)d_in[8 + 6 * l + 0];
    gb[l]  = (const float*)d_in[8 + 6 * l + 1];
    bng[l] = (const float*)d_in[8 + 6 * l + 2];
    bnb[l] = (const float*)d_in[8 + 6 * l + 3];
    bnm[l] = (const float*)d_in[8 + 6 * l + 4];
    bnv[l] = (const float*)d_in[8 + 6 * l + 5];
  }
  const int* srcp = ei;
  const int* dstp = ei + NE;

  char* w = (char*)d_ws;
  auto alloc = [&](size_t bytes) { char* p = w; w += (bytes + 255) & ~255ULL; return p; };
  int*   deg     = (int*)alloc((size_t)NN * 4);
  int*   offsets = (int*)alloc((size_t)NN * 4);
  int*   cursor  = (int*)alloc((size_t)NN * 4);
  int*   counter = (int*)alloc(256);
  int*   bins    = (int*)alloc(256 * 4);
  int*   binpos  = (int*)alloc(256 * 4);
  int*   order   = (int*)alloc((size_t)NN * 4);
  float* dinv    = (float*)alloc((size_t)NN * 4);
  int2*  adj     = (int2*)alloc((size_t)NE * 8);
  float* w1p     = (float*)alloc(96 * 128 * 4);
  float* bnscale = (float*)alloc(400 * 4);
  float* bnshift = (float*)alloc(400 * 4);
  float* bufA    = (float*)alloc((size_t)NN * 128 * 4);
  float* bufB    = (float*)alloc((size_t)NN * 128 * 4);
  float* bufC    = (float*)alloc((size_t)NN * 128 * 4);

  int nb_n = (NN + 255) / 256;
  int nb_e = (NE + 255) / 256;
  k_init<<<nb_n, 256, 0, stream>>>(deg, counter, bins, NN);
  k_count<<<nb_e, 256, 0, stream>>>(dstp, deg, NE);
  k_alloc<<<nb_n, 256, 0, stream>>>(deg, dinv, offsets, cursor, counter, NN);
  k_fill<<<nb_e, 256, 0, stream>>>(srcp, dstp, dinv, cursor, adj, NE);
  k_hist<<<nb_n, 256, 0, stream>>>(deg, bins, NN);
  k_scan<<<1, 256, 0, stream>>>(bins, binpos);
  k_scatter<<<nb_n, 256, 0, stream>>>(deg, binpos, order, NN);
  k_padw1<<<48, 256, 0, stream>>>(gw[0], w1p);
  {
    BNParams bp;
    for (int l = 0; l < 5; l++) {
      bp.bg[l] = bng[l]; bp.bv[l] = bnv[l]; bp.gb[l] = gb[l];
      bp.bm[l] = bnm[l]; bp.bb[l] = bnb[l];
    }
    k_bnprep<<<1, 512, 0, stream>>>(bp, bnscale, bnshift);
  }

  k_cnn<<<NN / 2, 256, 0, stream>>>(x, cw1, cb1, cw2, cb2, cw3, cb3, bufA);

  int gx = (NN + 63) / 64;
  // L1 (agg-first: fi=96 < fo=128): AH = A@H (96 cols), then GEMM + fused BN+tanh
  k_agg96<<<(NN + 31) / 32, 256, 0, stream>>>(bufA, offsets, deg, adj, dinv, order, bufB, NN);
  k_gemm<96, 128, 64, true><<<dim3(gx, 2), 256, 0, stream>>>(bufB, w1p, bufC, NN, bnscale, bnshift, 0);
  // L2: [N,128]@[128,128] then agg
  k_gemm<128, 128, 64><<<dim3(gx, 2), 256, 0, stream>>>(bufC, gw[1], bufB, NN);
  k_agg<128, false><<<(NN + 15) / 16, 256, 0, stream>>>(bufB, offsets, deg, adj, dinv, order,
                                                        bnscale, bnshift, 128, bufA, NN);
  // L3: [N,128]@[128,64] then agg
  k_gemm<128, 64, 64><<<dim3(gx, 1), 256, 0, stream>>>(bufA, gw[2], bufB, NN);
  k_agg<64, false><<<(NN + 31) / 32, 256, 0, stream>>>(bufB, offsets, deg, adj, dinv, order,
                                                       bnscale, bnshift, 256, bufC, NN);
  // L4: [N,64]@[64,64] then agg
  k_gemm<64, 64, 64><<<dim3(gx, 1), 256, 0, stream>>>(bufC, gw[3], bufB, NN);
  k_agg<64, false><<<(NN + 31) / 32, 256, 0, stream>>>(bufB, offsets, deg, adj, dinv, order,
                                                       bnscale, bnshift, 320, bufA, NN);
  // L5: [N,64]@[64,16] then agg + BN + softmax -> d_out
  k_gemm<64, 16, 16><<<dim3(gx, 1), 256, 0, stream>>>(bufA, gw[4], bufB, NN);
  k_agg<16, true><<<(NN + 127) / 128, 256, 0, stream>>>(bufB, offsets, deg, adj, dinv, order,
                                                        bnscale, bnshift, 384, (float*)d_out, NN);
}

// Round 11
// 1308.064 us; speedup vs baseline: 1.5192x; 1.5192x over previous
//
#include <hip/hip_runtime.h>
#include <math.h>

namespace {

constexpr int NN = 100000;
constexpr int NE = 1600000;
constexpr float EPS = 1e-5f;

// leaky(x) == max(x, 0.01x) for all x (2 instr: v_mul + v_max)
__device__ __forceinline__ float leaky(float x) { return fmaxf(x, 0.01f * x); }
__device__ __forceinline__ float ffma(float a, float b, float c) { return __builtin_fmaf(a, b, c); }

// ---------------- preprocessing: degrees, dinv, CSR-by-dst ----------------

__global__ __launch_bounds__(256) void k_init(int* __restrict__ deg, int* __restrict__ counter, int n) {
  int i = blockIdx.x * 256 + threadIdx.x;
  if (i < n) deg[i] = 1;          // self-loop
  if (i == 0) counter[0] = 0;
}

__global__ __launch_bounds__(256) void k_count(const int* __restrict__ dst, int* __restrict__ deg, int e) {
  int i = blockIdx.x * 256 + threadIdx.x;
  if (i < e) atomicAdd(&deg[dst[i]], 1);
}

// dinv = rsqrt(deg); allocate CSR slot ranges via wave-aggregated atomic
__global__ __launch_bounds__(256) void k_alloc(const int* __restrict__ deg, float* __restrict__ dinv,
                                               int* __restrict__ offsets, int* __restrict__ cursor,
                                               int* __restrict__ counter, int n) {
  int i = blockIdx.x * 256 + threadIdx.x;
  int lane = threadIdx.x & 63;
  int c = 0;
  if (i < n) {
    int d = deg[i];
    dinv[i] = rsqrtf((float)d);
    c = d - 1;                    // real in-edges only (self-loop handled analytically)
  }
  // wave inclusive scan
  int v = c;
#pragma unroll
  for (int s = 1; s < 64; s <<= 1) {
    int t = __shfl_up(v, s, 64);
    if (lane >= s) v += t;
  }
  int total = __shfl(v, 63, 64);
  int base = 0;
  if (lane == 63) base = atomicAdd(counter, total);
  base = __shfl(base, 63, 64);
  if (i < n) {
    int off = base + v - c;       // exclusive prefix
    offsets[i] = off;
    cursor[i] = off;
  }
}

// adj entry = (src, norm) fused in one int2 -> single 8B load per edge in k_agg
__global__ __launch_bounds__(256) void k_fill(const int* __restrict__ src, const int* __restrict__ dst,
                                              const float* __restrict__ dinv, int* __restrict__ cursor,
                                              int2* __restrict__ adj, int e) {
  int i = blockIdx.x * 256 + threadIdx.x;
  if (i < e) {
    int s = src[i], d = dst[i];
    int p = atomicAdd(&cursor[d], 1);
    adj[p] = make_int2(s, __float_as_int(dinv[s] * dinv[d]));
  }
}

// zero-pad gw1 [94][128] -> [96][128]
__global__ __launch_bounds__(256) void k_padw1(const float* __restrict__ gw1, float* __restrict__ w1p) {
  int i = blockIdx.x * 256 + threadIdx.x;
  if (i < 96 * 128) w1p[i] = (i < 94 * 128) ? gw1[i] : 0.f;
}

// precompute per-layer BN scale/shift: out = acc*scale + shift
// scale = bg*rsqrt(bv+EPS); shift = (gb-bm)*scale + bb   (gb = GCN bias, folded)
struct BNParams {
  const float* bg[5];
  const float* bv[5];
  const float* gb[5];
  const float* bm[5];
  const float* bb[5];
};
__global__ __launch_bounds__(512) void k_bnprep(BNParams p, float* __restrict__ scale, float* __restrict__ shift) {
  int i = threadIdx.x;                    // [0, 400)
  if (i >= 400) return;
  const int ends[5] = {128, 256, 320, 384, 400};
  int l = 0;
  while (i >= ends[l]) l++;
  int c = i - (l ? ends[l - 1] : 0);
  float sc = p.bg[l][c] * rsqrtf(p.bv[l][c] + EPS);
  scale[i] = sc;
  shift[i] = ffma(p.gb[l][c] - p.bm[l][c], sc, p.bb[l][c]);
}

// ---------------- CNN encoder ----------------
// (unchanged — 651 us, VALUBusy 93%, control kernel)
__global__ __launch_bounds__(256, 4) void k_cnn(const float* __restrict__ x,
                                             const float* __restrict__ cw1, const float* __restrict__ cb1,
                                             const float* __restrict__ cw2, const float* __restrict__ cb2,
                                             const float* __restrict__ cw3, const float* __restrict__ cb3,
                                             float* __restrict__ H) {
  __shared__ __align__(16) float inb[2][500];
  __shared__ float c1[2][2940];               // [10 ci][98 h][3 w]
  __shared__ float part[2][2][2][98];         // [node][co-wave][w][h] conv3 partials

  int tid = threadIdx.x;
  int half = tid >> 7;          // node within block (waves 0,1 -> node0; 2,3 -> node1)
  int nt = tid & 127;           // thread id within node
  int lane = tid & 63;
  int node = blockIdx.x * 2 + half;
  int co0 = __builtin_amdgcn_readfirstlane(((tid >> 6) & 1) * 10);  // wave-uniform co-group

  for (int i = tid; i < 2 * 2 * 2 * 98; i += 256) ((float*)part)[i] = 0.f;

  if (nt < 125) {
    const float4* xp = (const float4*)(x + (size_t)node * 500);
    ((float4*)inb[half])[nt] = xp[nt];
  }
  __syncthreads();

  {
    // conv1: one h-row per thread (h = nt, 98 rows), 3 w-outputs x 10 co.
    const float* in = inb[half];
    float* c1p = c1[half];
    int h = nt;
    if (h < 98) {
      float xv[3][5];
#pragma unroll
      for (int kh = 0; kh < 3; kh++)
#pragma unroll
        for (int c = 0; c < 5; c++) xv[kh][c] = in[(h + kh) * 5 + c];
      float* rowp = c1p + h * 3;
#pragma unroll
      for (int co = 0; co < 10; co++) {
        float b = cb1[co];
        float a0 = b, a1 = b, a2 = b;
#pragma unroll
        for (int kh = 0; kh < 3; kh++)
#pragma unroll
          for (int kw = 0; kw < 3; kw++) {
            float wv = cw1[co * 9 + kh * 3 + kw];
            a0 = ffma(xv[kh][kw + 0], wv, a0);
            a1 = ffma(xv[kh][kw + 1], wv, a1);
            a2 = ffma(xv[kh][kw + 2], wv, a2);
          }
        rowp[co * 294 + 0] = leaky(a0);
        rowp[co * 294 + 1] = leaky(a1);
        rowp[co * 294 + 2] = leaky(a2);
      }
    }
  }
  __syncthreads();

  // conv2: lane = hg*2 + w. Each lane: 3 h-rows x 1 w-col x 10 co (wave's co-group).
  int hg = lane >> 1, w = lane & 1;
  int h0 = hg * 3;
  float acc[3][10];
#pragma unroll
  for (int a = 0; a < 3; a++)
#pragma unroll
    for (int c = 0; c < 10; c++) acc[a][c] = 0.f;
  {
    const float* c1p = c1[half];
#pragma unroll 1
    for (int ci = 0; ci < 10; ci++) {
      float r[5][2];
      const float* base = c1p + ci * 294 + h0 * 3 + w;
#pragma unroll
      for (int i = 0; i < 5; i++) {
        r[i][0] = base[i * 3];
        r[i][1] = base[i * 3 + 1];
      }
#pragma unroll
      for (int c = 0; c < 10; c++) {
        const float* wp = cw2 + (co0 + c) * 60 + ci * 6;   // [co][ci][kh][kw]
        float w0 = wp[0], w1 = wp[1], w2v = wp[2], w3v = wp[3], w4 = wp[4], w5 = wp[5];
#pragma unroll
        for (int hh = 0; hh < 3; hh++) {
          float t = acc[hh][c];
          t = ffma(r[hh][0],     w0,  t);
          t = ffma(r[hh][1],     w1,  t);
          t = ffma(r[hh + 1][0], w2v, t);
          t = ffma(r[hh + 1][1], w3v, t);
          t = ffma(r[hh + 2][0], w4,  t);
          t = ffma(r[hh + 2][1], w5,  t);
          acc[hh][c] = t;
        }
      }
    }
#pragma unroll
    for (int c = 0; c < 10; c++) {
      float b = cb2[co0 + c];
#pragma unroll
      for (int hh = 0; hh < 3; hh++) acc[hh][c] = leaky(acc[hh][c] + b);
    }
  }
  __syncthreads();

  // conv3 fused via phased part[] accumulation
  {
    float* pp = &part[half][co0 == 0 ? 0 : 1][w][0];
#pragma unroll
    for (int kh = 0; kh < 3; kh++) {
      float ws[10];
#pragma unroll
      for (int c = 0; c < 10; c++) {
        float wa = cw3[(co0 + c) * 6 + kh * 2 + 0];   // scalar
        float wb = cw3[(co0 + c) * 6 + kh * 2 + 1];   // scalar
        ws[c] = w ? wb : wa;                          // v_cndmask
      }
#pragma unroll
      for (int hh = 0; hh < 3; hh++) {
        float s = 0.f;
#pragma unroll
        for (int c = 0; c < 10; c++) s = ffma(acc[hh][c], ws[c], s);
        pp[h0 + hh - kh + 2] += s;
      }
      __syncthreads();
    }
  }

  {
    float* Hp = H + (size_t)node * 96;
    if (nt < 94) {
      float v = part[half][0][0][nt + 2] + part[half][0][1][nt + 2]
              + part[half][1][0][nt + 2] + part[half][1][1][nt + 2] + cb3[0];
      Hp[nt] = tanhf(v);
    } else if (nt < 96) {
      Hp[nt] = 0.f;
    }
  }
}

// ---------------- GEMM: C[M,FO-tile] = A[M,K] @ W[K,FO] (+ optional BN+tanh epilogue) ----
// A staged k-major (As[K][68], 16B-aligned rows) so the K-loop reads the 4-row A
// fragment as ONE ds_read_b128 (broadcast across tx-lanes, conflict-free) instead of
// 4x ds_read_b32. LDS pipe per k-step: 35 -> 24 cyc/wave.
template <int K, int FO, int BN, bool EPI = false>
__global__ __launch_bounds__(256) void k_gemm(const float* __restrict__ A, const float* __restrict__ W,
                                              float* __restrict__ C, int M,
                                              const float* __restrict__ bns = nullptr,
                                              const float* __restrict__ bnh = nullptr,
                                              int bnofs = 0) {
  int tid = threadIdx.x;
  int row_base = blockIdx.x * 64;
  int col_base = blockIdx.y * BN;

  if constexpr (BN == 64) {
    __shared__ __align__(16) float As[K][68];   // k-major, pad 4 -> rows 16B aligned
    __shared__ __align__(16) float Ws[K][BN];
    constexpr int K4 = K / 4;
    for (int idx = tid; idx < 64 * K4; idx += 256) {
      int r = idx / K4, kk = idx - r * K4;
      int row = row_base + r;
      float4 a = make_float4(0.f, 0.f, 0.f, 0.f);
      if (row < M) a = *(const float4*)&A[(size_t)row * K + kk * 4];
      As[kk * 4 + 0][r] = a.x;
      As[kk * 4 + 1][r] = a.y;
      As[kk * 4 + 2][r] = a.z;
      As[kk * 4 + 3][r] = a.w;
    }
    for (int idx = tid; idx < K * BN; idx += 256) {
      int r = idx / BN, c = idx - r * BN;
      Ws[r][c] = W[r * FO + col_base + c];
    }
    __syncthreads();

    int ty = tid >> 4, tx = tid & 15;
    float acc[4][4] = {};
#pragma unroll 4
    for (int k = 0; k < K; k++) {
      const float4 a = *(const float4*)&As[k][ty * 4];
      const float4 b = *(const float4*)&Ws[k][tx * 4];
      acc[0][0] = ffma(a.x, b.x, acc[0][0]); acc[0][1] = ffma(a.x, b.y, acc[0][1]);
      acc[0][2] = ffma(a.x, b.z, acc[0][2]); acc[0][3] = ffma(a.x, b.w, acc[0][3]);
      acc[1][0] = ffma(a.y, b.x, acc[1][0]); acc[1][1] = ffma(a.y, b.y, acc[1][1]);
      acc[1][2] = ffma(a.y, b.z, acc[1][2]); acc[1][3] = ffma(a.y, b.w, acc[1][3]);
      acc[2][0] = ffma(a.z, b.x, acc[2][0]); acc[2][1] = ffma(a.z, b.y, acc[2][1]);
      acc[2][2] = ffma(a.z, b.z, acc[2][2]); acc[2][3] = ffma(a.z, b.w, acc[2][3]);
      acc[3][0] = ffma(a.w, b.x, acc[3][0]); acc[3][1] = ffma(a.w, b.y, acc[3][1]);
      acc[3][2] = ffma(a.w, b.z, acc[3][2]); acc[3][3] = ffma(a.w, b.w, acc[3][3]);
    }
    float4 s4, h4;
    if constexpr (EPI) {
      s4 = *(const float4*)&bns[bnofs + col_base + tx * 4];
      h4 = *(const float4*)&bnh[bnofs + col_base + tx * 4];
    }
#pragma unroll
    for (int i = 0; i < 4; i++) {
      int row = row_base + ty * 4 + i;
      if (row < M) {
        float4 v;
        if constexpr (EPI) {
          v.x = tanhf(ffma(acc[i][0], s4.x, h4.x));
          v.y = tanhf(ffma(acc[i][1], s4.y, h4.y));
          v.z = tanhf(ffma(acc[i][2], s4.z, h4.z));
          v.w = tanhf(ffma(acc[i][3], s4.w, h4.w));
        } else {
          v = make_float4(acc[i][0], acc[i][1], acc[i][2], acc[i][3]);
        }
        *(float4*)&C[(size_t)row * FO + col_base + tx * 4] = v;
      }
    }
  } else {  // BN == 16: thread = 1 row x 4 cols (tiny L5 GEMM, row-major As as before)
    __shared__ float As[64][K + 1];
    __shared__ __align__(16) float Ws[K][BN];
    for (int idx = tid; idx < 64 * K; idx += 256) {
      int r = idx / K, k = idx - r * K;
      int row = row_base + r;
      As[r][k] = (row < M) ? A[(size_t)row * K + k] : 0.f;
    }
    for (int idx = tid; idx < K * BN; idx += 256) {
      int r = idx / BN, c = idx - r * BN;
      Ws[r][c] = W[r * FO + col_base + c];
    }
    __syncthreads();

    int ty = tid >> 2, tx = tid & 3;
    float acc[4] = {};
#pragma unroll 4
    for (int k = 0; k < K; k++) {
      float a = As[ty][k];
      const float4 b = *(const float4*)&Ws[k][tx * 4];
      acc[0] = ffma(a, b.x, acc[0]); acc[1] = ffma(a, b.y, acc[1]);
      acc[2] = ffma(a, b.z, acc[2]); acc[3] = ffma(a, b.w, acc[3]);
    }
    int row = row_base + ty;
    if (row < M) *(float4*)&C[(size_t)row * FO + col_base + tx * 4] = make_float4(acc[0], acc[1], acc[2], acc[3]);
  }
}

// ---------------- plain aggregation for L1 (FO=96): AH = A_norm @ H ----------------
// 8 lanes/node x 12 cols (3 float4). In-order nodes (R10 lesson: order permutation
// destroys write/adjacency locality, +590 us).
__global__ __launch_bounds__(256) void k_agg96(const float* __restrict__ Hm,
                                               const int* __restrict__ offsets, const int* __restrict__ deg,
                                               const int2* __restrict__ adj,
                                               const float* __restrict__ dinv,
                                               float* __restrict__ out, int n) {
  int tid = threadIdx.x;
  int li = tid >> 3, c12 = (tid & 7) * 12;
  int node = blockIdx.x * 32 + li;
  if (node >= n) return;

  float dv = dinv[node];
  float se = dv * dv;
  const float4* sp = (const float4*)&Hm[(size_t)node * 96 + c12];
  float4 a0 = sp[0], a1 = sp[1], a2 = sp[2];
  a0.x *= se; a0.y *= se; a0.z *= se; a0.w *= se;
  a1.x *= se; a1.y *= se; a1.z *= se; a1.w *= se;
  a2.x *= se; a2.y *= se; a2.z *= se; a2.w *= se;

  const int2* ap = adj + offsets[node];
  int cnt = deg[node] - 1;
  int e = 0;
  for (; e + 1 < cnt; e += 2) {
    int2 e0 = ap[e], e1 = ap[e + 1];
    float n0 = __int_as_float(e0.y), n1 = __int_as_float(e1.y);
    const float4* q0 = (const float4*)&Hm[(size_t)e0.x * 96 + c12];
    const float4* q1 = (const float4*)&Hm[(size_t)e1.x * 96 + c12];
    float4 u0 = q0[0], u1 = q0[1], u2 = q0[2];
    float4 v0 = q1[0], v1 = q1[1], v2 = q1[2];
    a0.x = ffma(u0.x, n0, a0.x); a0.y = ffma(u0.y, n0, a0.y);
    a0.z = ffma(u0.z, n0, a0.z); a0.w = ffma(u0.w, n0, a0.w);
    a1.x = ffma(u1.x, n0, a1.x); a1.y = ffma(u1.y, n0, a1.y);
    a1.z = ffma(u1.z, n0, a1.z); a1.w = ffma(u1.w, n0, a1.w);
    a2.x = ffma(u2.x, n0, a2.x); a2.y = ffma(u2.y, n0, a2.y);
    a2.z = ffma(u2.z, n0, a2.z); a2.w = ffma(u2.w, n0, a2.w);
    a0.x = ffma(v0.x, n1, a0.x); a0.y = ffma(v0.y, n1, a0.y);
    a0.z = ffma(v0.z, n1, a0.z); a0.w = ffma(v0.w, n1, a0.w);
    a1.x = ffma(v1.x, n1, a1.x); a1.y = ffma(v1.y, n1, a1.y);
    a1.z = ffma(v1.z, n1, a1.z); a1.w = ffma(v1.w, n1, a1.w);
    a2.x = ffma(v2.x, n1, a2.x); a2.y = ffma(v2.y, n1, a2.y);
    a2.z = ffma(v2.z, n1, a2.z); a2.w = ffma(v2.w, n1, a2.w);
  }
  if (e < cnt) {
    int2 e0 = ap[e];
    float n0 = __int_as_float(e0.y);
    const float4* q0 = (const float4*)&Hm[(size_t)e0.x * 96 + c12];
    float4 u0 = q0[0], u1 = q0[1], u2 = q0[2];
    a0.x = ffma(u0.x, n0, a0.x); a0.y = ffma(u0.y, n0, a0.y);
    a0.z = ffma(u0.z, n0, a0.z); a0.w = ffma(u0.w, n0, a0.w);
    a1.x = ffma(u1.x, n0, a1.x); a1.y = ffma(u1.y, n0, a1.y);
    a1.z = ffma(u1.z, n0, a1.z); a1.w = ffma(u1.w, n0, a1.w);
    a2.x = ffma(u2.x, n0, a2.x); a2.y = ffma(u2.y, n0, a2.y);
    a2.z = ffma(u2.z, n0, a2.z); a2.w = ffma(u2.w, n0, a2.w);
  }
  float4* op = (float4*)&out[(size_t)node * 96 + c12];
  op[0] = a0; op[1] = a1; op[2] = a2;
}

// ---------------- aggregation + BN (+tanh | +softmax) ----------------
// 8 cols/thread; 1 int2 adj load per edge; edge loop unrolled x4; in-order nodes.
template <int FO, bool SOFT>
__global__ __launch_bounds__(256) void k_agg(const float* __restrict__ XW,
                                             const int* __restrict__ offsets, const int* __restrict__ deg,
                                             const int2* __restrict__ adj,
                                             const float* __restrict__ dinv,
                                             const float* __restrict__ bnscale, const float* __restrict__ bnshift,
                                             int bnofs, float* __restrict__ out, int n) {
  constexpr int TPN = FO / 8;          // threads per node
  constexpr int NPB = 256 / TPN;       // nodes per block
  int tid = threadIdx.x;
  int li = tid / TPN, c8 = (tid % TPN) * 8;
  int node = blockIdx.x * NPB + li;
  if (node >= n) return;

  float dv = dinv[node];
  float se = dv * dv;
  const float4* selfp = (const float4*)&XW[(size_t)node * FO + c8];
  float4 aL = selfp[0], aH = selfp[1];
  aL.x *= se; aL.y *= se; aL.z *= se; aL.w *= se;
  aH.x *= se; aH.y *= se; aH.z *= se; aH.w *= se;

  const int2* ap = adj + offsets[node];
  int cnt = deg[node] - 1;
  int e = 0;
#define EDGE_STEP(AA)                                                        \
  {                                                                          \
    float nm = __int_as_float((AA).y);                                       \
    const float4* q = (const float4*)&XW[(size_t)(AA).x * FO + c8];          \
    float4 v = q[0], w = q[1];                                               \
    aL.x = ffma(v.x, nm, aL.x); aL.y = ffma(v.y, nm, aL.y);                  \
    aL.z = ffma(v.z, nm, aL.z); aL.w = ffma(v.w, nm, aL.w);                  \
    aH.x = ffma(w.x, nm, aH.x); aH.y = ffma(w.y, nm, aH.y);                  \
    aH.z = ffma(w.z, nm, aH.z); aH.w = ffma(w.w, nm, aH.w);                  \
  }
  for (; e + 3 < cnt; e += 4) {
    int2 a0 = ap[e], a1 = ap[e + 1], a2 = ap[e + 2], a3 = ap[e + 3];
    EDGE_STEP(a0); EDGE_STEP(a1); EDGE_STEP(a2); EDGE_STEP(a3);
  }
  for (; e < cnt; e++) {
    int2 a0 = ap[e];
    EDGE_STEP(a0);
  }
#undef EDGE_STEP

  const float4 s4L = *(const float4*)&bnscale[bnofs + c8];
  const float4 s4H = *(const float4*)&bnscale[bnofs + c8 + 4];
  const float4 h4L = *(const float4*)&bnshift[bnofs + c8];
  const float4 h4H = *(const float4*)&bnshift[bnofs + c8 + 4];
  float r[8];
  r[0] = ffma(aL.x, s4L.x, h4L.x); r[1] = ffma(aL.y, s4L.y, h4L.y);
  r[2] = ffma(aL.z, s4L.z, h4L.z); r[3] = ffma(aL.w, s4L.w, h4L.w);
  r[4] = ffma(aH.x, s4H.x, h4H.x); r[5] = ffma(aH.y, s4H.y, h4H.y);
  r[6] = ffma(aH.z, s4H.z, h4H.z); r[7] = ffma(aH.w, s4H.w, h4H.w);

  float4 oL, oH;
  if constexpr (SOFT) {
    float mx = r[0];
#pragma unroll
    for (int i = 1; i < 8; i++) mx = fmaxf(mx, r[i]);
#pragma unroll
    for (int m = TPN / 2; m; m >>= 1) mx = fmaxf(mx, __shfl_xor(mx, m, TPN));
    float sm = 0.f;
#pragma unroll
    for (int i = 0; i < 8; i++) { r[i] = expf(r[i] - mx); sm += r[i]; }
#pragma unroll
    for (int m = TPN / 2; m; m >>= 1) sm += __shfl_xor(sm, m, TPN);
    float inv = 1.f / sm;
#pragma unroll
    for (int i = 0; i < 8; i++) r[i] *= inv;
  } else {
#pragma unroll
    for (int i = 0; i < 8; i++) r[i] = tanhf(r[i]);
  }
  oL = make_float4(r[0], r[1], r[2], r[3]);
  oH = make_float4(r[4], r[5], r[6], r[7]);
  float4* op = (float4*)&out[(size_t)node * FO + c8];
  op[0] = oL;
  op[1] = oH;
}

}  // namespace

extern "C" void kernel_launch(void* const* d_in, const int* in_sizes, int n_in,
                              void* d_out, int out_size, void* d_ws, size_t ws_size,
                              hipStream_t stream) {
  const float* x   = (const float*)d_in[0];
  const int*   ei  = (const int*)d_in[1];
  const float* cw1 = (const float*)d_in[2];
  const float* cb1 = (const float*)d_in[3];
  const float* cw2 = (const float*)d_in[4];
  const float* cb2 = (const float*)d_in[5];
  const float* cw3 = (const float*)d_in[6];
  const float* cb3 = (const float*)d_in[7];
  const float *gw[5], *gb[5], *bng[5], *bnb[5], *bnm[5], *bnv[5];
  for (int l = 0; l < 5; l++) {
    gw[l]  = (const float*)d_in[8 + 6 * l + 0];
    gb[l]  = (const float*)d_in[8 + 6 * l + 1];
    bng[l] = (const float*)d_in[8 + 6 * l + 2];
    bnb[l] = (const float*)d_in[8 + 6 * l + 3];
    bnm[l] = (const float*)d_in[8 + 6 * l + 4];
    bnv[l] = (const float*)d_in[8 + 6 * l + 5];
  }
  const int* srcp = ei;
  const int* dstp = ei + NE;

  char* w = (char*)d_ws;
  auto alloc = [&](size_t bytes) { char* p = w; w += (bytes + 255) & ~255ULL; return p; };
  int*   deg     = (int*)alloc((size_t)NN * 4);
  int*   offsets = (int*)alloc((size_t)NN * 4);
  int*   cursor  = (int*)alloc((size_t)NN * 4);
  int*   counter = (int*)alloc(256);
  float* dinv    = (float*)alloc((size_t)NN * 4);
  int2*  adj     = (int2*)alloc((size_t)NE * 8);
  float* w1p     = (float*)alloc(96 * 128 * 4);
  float* bnscale = (float*)alloc(400 * 4);
  float* bnshift = (float*)alloc(400 * 4);
  float* bufA    = (float*)alloc((size_t)NN * 128 * 4);
  float* bufB    = (float*)alloc((size_t)NN * 128 * 4);
  float* bufC    = (float*)alloc((size_t)NN * 128 * 4);

  int nb_n = (NN + 255) / 256;
  int nb_e = (NE + 255) / 256;
  k_init<<<nb_n, 256, 0, stream>>>(deg, counter, NN);
  k_count<<<nb_e, 256, 0, stream>>>(dstp, deg, NE);
  k_alloc<<<nb_n, 256, 0, stream>>>(deg, dinv, offsets, cursor, counter, NN);
  k_fill<<<nb_e, 256, 0, stream>>>(srcp, dstp, dinv, cursor, adj, NE);
  k_padw1<<<48, 256, 0, stream>>>(gw[0], w1p);
  {
    BNParams bp;
    for (int l = 0; l < 5; l++) {
      bp.bg[l] = bng[l]; bp.bv[l] = bnv[l]; bp.gb[l] = gb[l];
      bp.bm[l] = bnm[l]; bp.bb[l] = bnb[l];
    }
    k_bnprep<<<1, 512, 0, stream>>>(bp, bnscale, bnshift);
  }

  k_cnn<<<NN / 2, 256, 0, stream>>>(x, cw1, cb1, cw2, cb2, cw3, cb3, bufA);

  int gx = (NN + 63) / 64;
  // L1 (agg-first: fi=96 < fo=128): AH = A@H (96 cols), then GEMM + fused BN+tanh
  k_agg96<<<(NN + 31) / 32, 256, 0, stream>>>(bufA, offsets, deg, adj, dinv, bufB, NN);
  k_gemm<96, 128, 64, true><<<dim3(gx, 2), 256, 0, stream>>>(bufB, w1p, bufC, NN, bnscale, bnshift, 0);
  // L2: [N,128]@[128,128] then agg
  k_gemm<128, 128, 64><<<dim3(gx, 2), 256, 0, stream>>>(bufC, gw[1], bufB, NN);
  k_agg<128, false><<<(NN + 15) / 16, 256, 0, stream>>>(bufB, offsets, deg, adj, dinv,
                                                        bnscale, bnshift, 128, bufA, NN);
  // L3: [N,128]@[128,64] then agg
  k_gemm<128, 64, 64><<<dim3(gx, 1), 256, 0, stream>>>(bufA, gw[2], bufB, NN);
  k_agg<64, false><<<(NN + 31) / 32, 256, 0, stream>>>(bufB, offsets, deg, adj, dinv,
                                                       bnscale, bnshift, 256, bufC, NN);
  // L4: [N,64]@[64,64] then agg
  k_gemm<64, 64, 64><<<dim3(gx, 1), 256, 0, stream>>>(bufC, gw[3], bufB, NN);
  k_agg<64, false><<<(NN + 31) / 32, 256, 0, stream>>>(bufB, offsets, deg, adj, dinv,
                                                       bnscale, bnshift, 320, bufA, NN);
  // L5: [N,64]@[64,16] then agg + BN + softmax -> d_out
  k_gemm<64, 16, 16><<<dim3(gx, 1), 256, 0, stream>>>(bufA, gw[4], bufB, NN);
  k_agg<16, true><<<(NN + 127) / 128, 256, 0, stream>>>(bufB, offsets, deg, adj, dinv,
                                                        bnscale, bnshift, 384, (float*)d_out, NN);
}

// Round 12
// 1295.272 us; speedup vs baseline: 1.5342x; 1.0099x over previous
//
#include <hip/hip_runtime.h>
#include <math.h>

namespace {

constexpr int NN = 100000;
constexpr int NE = 1600000;
constexpr float EPS = 1e-5f;

__device__ __forceinline__ float leaky(float x) { return fmaxf(x, 0.01f * x); }
__device__ __forceinline__ float ffma(float a, float b, float c) { return __builtin_fmaf(a, b, c); }

// ---------------- preprocessing: degrees, dinv, CSR-by-dst ----------------

__global__ __launch_bounds__(256) void k_init(int* __restrict__ deg, int* __restrict__ counter, int n) {
  int i = blockIdx.x * 256 + threadIdx.x;
  if (i < n) deg[i] = 1;          // self-loop
  if (i == 0) counter[0] = 0;
}

__global__ __launch_bounds__(256) void k_count(const int* __restrict__ dst, int* __restrict__ deg, int e) {
  int i = blockIdx.x * 256 + threadIdx.x;
  if (i < e) atomicAdd(&deg[dst[i]], 1);
}

__global__ __launch_bounds__(256) void k_alloc(const int* __restrict__ deg, float* __restrict__ dinv,
                                               int* __restrict__ offsets, int* __restrict__ cursor,
                                               int* __restrict__ counter, int n) {
  int i = blockIdx.x * 256 + threadIdx.x;
  int lane = threadIdx.x & 63;
  int c = 0;
  if (i < n) {
    int d = deg[i];
    dinv[i] = rsqrtf((float)d);
    c = d - 1;
  }
  int v = c;
#pragma unroll
  for (int s = 1; s < 64; s <<= 1) {
    int t = __shfl_up(v, s, 64);
    if (lane >= s) v += t;
  }
  int total = __shfl(v, 63, 64);
  int base = 0;
  if (lane == 63) base = atomicAdd(counter, total);
  base = __shfl(base, 63, 64);
  if (i < n) {
    int off = base + v - c;
    offsets[i] = off;
    cursor[i] = off;
  }
}

__global__ __launch_bounds__(256) void k_fill(const int* __restrict__ src, const int* __restrict__ dst,
                                              const float* __restrict__ dinv, int* __restrict__ cursor,
                                              int2* __restrict__ adj, int e) {
  int i = blockIdx.x * 256 + threadIdx.x;
  if (i < e) {
    int s = src[i], d = dst[i];
    int p = atomicAdd(&cursor[d], 1);
    adj[p] = make_int2(s, __float_as_int(dinv[s] * dinv[d]));
  }
}

__global__ __launch_bounds__(256) void k_padw1(const float* __restrict__ gw1, float* __restrict__ w1p) {
  int i = blockIdx.x * 256 + threadIdx.x;
  if (i < 96 * 128) w1p[i] = (i < 94 * 128) ? gw1[i] : 0.f;
}

struct BNParams {
  const float* bg[5];
  const float* bv[5];
  const float* gb[5];
  const float* bm[5];
  const float* bb[5];
};
__global__ __launch_bounds__(512) void k_bnprep(BNParams p, float* __restrict__ scale, float* __restrict__ shift) {
  int i = threadIdx.x;
  if (i >= 400) return;
  const int ends[5] = {128, 256, 320, 384, 400};
  int l = 0;
  while (i >= ends[l]) l++;
  int c = i - (l ? ends[l - 1] : 0);
  float sc = p.bg[l][c] * rsqrtf(p.bv[l][c] + EPS);
  scale[i] = sc;
  shift[i] = ffma(p.gb[l][c] - p.bm[l][c], sc, p.bb[l][c]);
}

// ---------------- CNN encoder ----------------
// (unchanged — 651 us, VALUBusy 93%, control kernel)
__global__ __launch_bounds__(256, 4) void k_cnn(const float* __restrict__ x,
                                             const float* __restrict__ cw1, const float* __restrict__ cb1,
                                             const float* __restrict__ cw2, const float* __restrict__ cb2,
                                             const float* __restrict__ cw3, const float* __restrict__ cb3,
                                             float* __restrict__ H) {
  __shared__ __align__(16) float inb[2][500];
  __shared__ float c1[2][2940];
  __shared__ float part[2][2][2][98];

  int tid = threadIdx.x;
  int half = tid >> 7;
  int nt = tid & 127;
  int lane = tid & 63;
  int node = blockIdx.x * 2 + half;
  int co0 = __builtin_amdgcn_readfirstlane(((tid >> 6) & 1) * 10);

  for (int i = tid; i < 2 * 2 * 2 * 98; i += 256) ((float*)part)[i] = 0.f;

  if (nt < 125) {
    const float4* xp = (const float4*)(x + (size_t)node * 500);
    ((float4*)inb[half])[nt] = xp[nt];
  }
  __syncthreads();

  {
    const float* in = inb[half];
    float* c1p = c1[half];
    int h = nt;
    if (h < 98) {
      float xv[3][5];
#pragma unroll
      for (int kh = 0; kh < 3; kh++)
#pragma unroll
        for (int c = 0; c < 5; c++) xv[kh][c] = in[(h + kh) * 5 + c];
      float* rowp = c1p + h * 3;
#pragma unroll
      for (int co = 0; co < 10; co++) {
        float b = cb1[co];
        float a0 = b, a1 = b, a2 = b;
#pragma unroll
        for (int kh = 0; kh < 3; kh++)
#pragma unroll
          for (int kw = 0; kw < 3; kw++) {
            float wv = cw1[co * 9 + kh * 3 + kw];
            a0 = ffma(xv[kh][kw + 0], wv, a0);
            a1 = ffma(xv[kh][kw + 1], wv, a1);
            a2 = ffma(xv[kh][kw + 2], wv, a2);
          }
        rowp[co * 294 + 0] = leaky(a0);
        rowp[co * 294 + 1] = leaky(a1);
        rowp[co * 294 + 2] = leaky(a2);
      }
    }
  }
  __syncthreads();

  int hg = lane >> 1, w = lane & 1;
  int h0 = hg * 3;
  float acc[3][10];
#pragma unroll
  for (int a = 0; a < 3; a++)
#pragma unroll
    for (int c = 0; c < 10; c++) acc[a][c] = 0.f;
  {
    const float* c1p = c1[half];
#pragma unroll 1
    for (int ci = 0; ci < 10; ci++) {
      float r[5][2];
      const float* base = c1p + ci * 294 + h0 * 3 + w;
#pragma unroll
      for (int i = 0; i < 5; i++) {
        r[i][0] = base[i * 3];
        r[i][1] = base[i * 3 + 1];
      }
#pragma unroll
      for (int c = 0; c < 10; c++) {
        const float* wp = cw2 + (co0 + c) * 60 + ci * 6;
        float w0 = wp[0], w1 = wp[1], w2v = wp[2], w3v = wp[3], w4 = wp[4], w5 = wp[5];
#pragma unroll
        for (int hh = 0; hh < 3; hh++) {
          float t = acc[hh][c];
          t = ffma(r[hh][0],     w0,  t);
          t = ffma(r[hh][1],     w1,  t);
          t = ffma(r[hh + 1][0], w2v, t);
          t = ffma(r[hh + 1][1], w3v, t);
          t = ffma(r[hh + 2][0], w4,  t);
          t = ffma(r[hh + 2][1], w5,  t);
          acc[hh][c] = t;
        }
      }
    }
#pragma unroll
    for (int c = 0; c < 10; c++) {
      float b = cb2[co0 + c];
#pragma unroll
      for (int hh = 0; hh < 3; hh++) acc[hh][c] = leaky(acc[hh][c] + b);
    }
  }
  __syncthreads();

  {
    float* pp = &part[half][co0 == 0 ? 0 : 1][w][0];
#pragma unroll
    for (int kh = 0; kh < 3; kh++) {
      float ws[10];
#pragma unroll
      for (int c = 0; c < 10; c++) {
        float wa = cw3[(co0 + c) * 6 + kh * 2 + 0];
        float wb = cw3[(co0 + c) * 6 + kh * 2 + 1];
        ws[c] = w ? wb : wa;
      }
#pragma unroll
      for (int hh = 0; hh < 3; hh++) {
        float s = 0.f;
#pragma unroll
        for (int c = 0; c < 10; c++) s = ffma(acc[hh][c], ws[c], s);
        pp[h0 + hh - kh + 2] += s;
      }
      __syncthreads();
    }
  }

  {
    float* Hp = H + (size_t)node * 96;
    if (nt < 94) {
      float v = part[half][0][0][nt + 2] + part[half][0][1][nt + 2]
              + part[half][1][0][nt + 2] + part[half][1][1][nt + 2] + cb3[0];
      Hp[nt] = tanhf(v);
    } else if (nt < 96) {
      Hp[nt] = 0.f;
    }
  }
}

// ---------------- big GEMM: C[M,FO] = A[M,K] @ W[K,FO] (+ optional BN+tanh epilogue) ----
// 128-row tiles, 8 rows x CPT cols per thread (CPT = BN/16: 8 for BN=128, 4 for BN=64).
// K-split staging (KT = K/2) keeps LDS at 25-68 KB -> 2-6 blocks/CU. A staged k-major
// so the a-fragment is one ds_read_b128 (4 distinct chunks/wave, broadcast). LDS reads
// per FMA halved vs 64x64/4x4; staging traffic per output halved in both panels.
// k ascending per output element -> bit-identical to previous rounds.
template <int K, int FO, int BN, bool EPI = false>
__global__ __launch_bounds__(256) void k_gemm2(const float* __restrict__ A, const float* __restrict__ W,
                                               float* __restrict__ C, int M,
                                               const float* __restrict__ bns = nullptr,
                                               const float* __restrict__ bnh = nullptr,
                                               int bnofs = 0) {
  constexpr int BM = 128;
  constexpr int KT = K / 2;
  constexpr int CPT = BN / 16;              // cols per thread (8 or 4)
  __shared__ __align__(16) float As[KT][BM + 4];
  __shared__ __align__(16) float Ws[KT][BN + 4];
  int tid = threadIdx.x;
  int row_base = blockIdx.x * BM;
  int col_base = blockIdx.y * BN;
  int ty = tid >> 4, tx = tid & 15;

  float acc[8][CPT];
#pragma unroll
  for (int i = 0; i < 8; i++)
#pragma unroll
    for (int j = 0; j < CPT; j++) acc[i][j] = 0.f;

#pragma unroll 1
  for (int kh = 0; kh < 2; kh++) {
    if (kh) __syncthreads();               // all reads of previous half done
    // stage A (k-major) for k in [kh*KT, kh*KT+KT)
    constexpr int K4 = KT / 4;
    for (int idx = tid; idx < BM * K4; idx += 256) {
      int r = idx / K4, kk = idx - r * K4;
      int row = row_base + r;
      float4 a = make_float4(0.f, 0.f, 0.f, 0.f);
      if (row < M) a = *(const float4*)&A[(size_t)row * K + kh * KT + kk * 4];
      As[kk * 4 + 0][r] = a.x;
      As[kk * 4 + 1][r] = a.y;
      As[kk * 4 + 2][r] = a.z;
      As[kk * 4 + 3][r] = a.w;
    }
    // stage W row-major
    constexpr int B4 = BN / 4;
    for (int idx = tid; idx < KT * B4; idx += 256) {
      int r = idx / B4, c4 = idx - r * B4;
      float4 wv = *(const float4*)&W[(size_t)(kh * KT + r) * FO + col_base + c4 * 4];
      *(float4*)&Ws[r][c4 * 4] = wv;
    }
    __syncthreads();

#pragma unroll 2
    for (int k = 0; k < KT; k++) {
      const float4 a0 = *(const float4*)&As[k][ty * 8];
      const float4 a1 = *(const float4*)&As[k][ty * 8 + 4];
      float ar[8] = {a0.x, a0.y, a0.z, a0.w, a1.x, a1.y, a1.z, a1.w};
      float bc[CPT];
      {
        const float4 b0 = *(const float4*)&Ws[k][tx * CPT];
        bc[0] = b0.x; bc[1] = b0.y; bc[2] = b0.z; bc[3] = b0.w;
        if constexpr (CPT == 8) {
          const float4 b1 = *(const float4*)&Ws[k][tx * CPT + 4];
          bc[4] = b1.x; bc[5] = b1.y; bc[6] = b1.z; bc[7] = b1.w;
        }
      }
#pragma unroll
      for (int i = 0; i < 8; i++)
#pragma unroll
        for (int j = 0; j < CPT; j++) acc[i][j] = ffma(ar[i], bc[j], acc[i][j]);
    }
  }

  // epilogue
  float s[CPT], h[CPT];
  if constexpr (EPI) {
    const float4 s0 = *(const float4*)&bns[bnofs + col_base + tx * CPT];
    const float4 h0 = *(const float4*)&bnh[bnofs + col_base + tx * CPT];
    s[0] = s0.x; s[1] = s0.y; s[2] = s0.z; s[3] = s0.w;
    h[0] = h0.x; h[1] = h0.y; h[2] = h0.z; h[3] = h0.w;
    if constexpr (CPT == 8) {
      const float4 s1 = *(const float4*)&bns[bnofs + col_base + tx * CPT + 4];
      const float4 h1 = *(const float4*)&bnh[bnofs + col_base + tx * CPT + 4];
      s[4] = s1.x; s[5] = s1.y; s[6] = s1.z; s[7] = s1.w;
      h[4] = h1.x; h[5] = h1.y; h[6] = h1.z; h[7] = h1.w;
    }
  }
#pragma unroll
  for (int i = 0; i < 8; i++) {
    int row = row_base + ty * 8 + i;
    if (row < M) {
      float o[CPT];
#pragma unroll
      for (int j = 0; j < CPT; j++) {
        if constexpr (EPI) o[j] = tanhf(ffma(acc[i][j], s[j], h[j]));
        else               o[j] = acc[i][j];
      }
      float* cp = &C[(size_t)row * FO + col_base + tx * CPT];
      *(float4*)cp = make_float4(o[0], o[1], o[2], o[3]);
      if constexpr (CPT == 8) *(float4*)(cp + 4) = make_float4(o[4], o[5], o[6], o[7]);
    }
  }
}

// ---------------- tiny L5 GEMM: [N,64]@[64,16] ----------------
__global__ __launch_bounds__(256) void k_gemm16(const float* __restrict__ A, const float* __restrict__ W,
                                                float* __restrict__ C, int M) {
  constexpr int K = 64, FO = 16;
  __shared__ float As[64][K + 1];
  __shared__ __align__(16) float Ws[K][FO];
  int tid = threadIdx.x;
  int row_base = blockIdx.x * 64;

  for (int idx = tid; idx < 64 * K; idx += 256) {
    int r = idx / K, k = idx - r * K;
    int row = row_base + r;
    As[r][k] = (row < M) ? A[(size_t)row * K + k] : 0.f;
  }
  for (int idx = tid; idx < K * FO; idx += 256) {
    int r = idx / FO, c = idx - r * FO;
    Ws[r][c] = W[r * FO + c];
  }
  __syncthreads();

  int ty = tid >> 2, tx = tid & 3;
  float acc[4] = {};
#pragma unroll 4
  for (int k = 0; k < K; k++) {
    float a = As[ty][k];
    const float4 b = *(const float4*)&Ws[k][tx * 4];
    acc[0] = ffma(a, b.x, acc[0]); acc[1] = ffma(a, b.y, acc[1]);
    acc[2] = ffma(a, b.z, acc[2]); acc[3] = ffma(a, b.w, acc[3]);
  }
  int row = row_base + ty;
  if (row < M) *(float4*)&C[(size_t)row * FO + tx * 4] = make_float4(acc[0], acc[1], acc[2], acc[3]);
}

// ---------------- plain aggregation for L1 (FO=96): AH = A_norm @ H ----------------
__global__ __launch_bounds__(256) void k_agg96(const float* __restrict__ Hm,
                                               const int* __restrict__ offsets, const int* __restrict__ deg,
                                               const int2* __restrict__ adj,
                                               const float* __restrict__ dinv,
                                               float* __restrict__ out, int n) {
  int tid = threadIdx.x;
  int li = tid >> 3, c12 = (tid & 7) * 12;
  int node = blockIdx.x * 32 + li;
  if (node >= n) return;

  float dv = dinv[node];
  float se = dv * dv;
  const float4* sp = (const float4*)&Hm[(size_t)node * 96 + c12];
  float4 a0 = sp[0], a1 = sp[1], a2 = sp[2];
  a0.x *= se; a0.y *= se; a0.z *= se; a0.w *= se;
  a1.x *= se; a1.y *= se; a1.z *= se; a1.w *= se;
  a2.x *= se; a2.y *= se; a2.z *= se; a2.w *= se;

  const int2* ap = adj + offsets[node];
  int cnt = deg[node] - 1;
  int e = 0;
  for (; e + 1 < cnt; e += 2) {
    int2 e0 = ap[e], e1 = ap[e + 1];
    float n0 = __int_as_float(e0.y), n1 = __int_as_float(e1.y);
    const float4* q0 = (const float4*)&Hm[(size_t)e0.x * 96 + c12];
    const float4* q1 = (const float4*)&Hm[(size_t)e1.x * 96 + c12];
    float4 u0 = q0[0], u1 = q0[1], u2 = q0[2];
    float4 v0 = q1[0], v1 = q1[1], v2 = q1[2];
    a0.x = ffma(u0.x, n0, a0.x); a0.y = ffma(u0.y, n0, a0.y);
    a0.z = ffma(u0.z, n0, a0.z); a0.w = ffma(u0.w, n0, a0.w);
    a1.x = ffma(u1.x, n0, a1.x); a1.y = ffma(u1.y, n0, a1.y);
    a1.z = ffma(u1.z, n0, a1.z); a1.w = ffma(u1.w, n0, a1.w);
    a2.x = ffma(u2.x, n0, a2.x); a2.y = ffma(u2.y, n0, a2.y);
    a2.z = ffma(u2.z, n0, a2.z); a2.w = ffma(u2.w, n0, a2.w);
    a0.x = ffma(v0.x, n1, a0.x); a0.y = ffma(v0.y, n1, a0.y);
    a0.z = ffma(v0.z, n1, a0.z); a0.w = ffma(v0.w, n1, a0.w);
    a1.x = ffma(v1.x, n1, a1.x); a1.y = ffma(v1.y, n1, a1.y);
    a1.z = ffma(v1.z, n1, a1.z); a1.w = ffma(v1.w, n1, a1.w);
    a2.x = ffma(v2.x, n1, a2.x); a2.y = ffma(v2.y, n1, a2.y);
    a2.z = ffma(v2.z, n1, a2.z); a2.w = ffma(v2.w, n1, a2.w);
  }
  if (e < cnt) {
    int2 e0 = ap[e];
    float n0 = __int_as_float(e0.y);
    const float4* q0 = (const float4*)&Hm[(size_t)e0.x * 96 + c12];
    float4 u0 = q0[0], u1 = q0[1], u2 = q0[2];
    a0.x = ffma(u0.x, n0, a0.x); a0.y = ffma(u0.y, n0, a0.y);
    a0.z = ffma(u0.z, n0, a0.z); a0.w = ffma(u0.w, n0, a0.w);
    a1.x = ffma(u1.x, n0, a1.x); a1.y = ffma(u1.y, n0, a1.y);
    a1.z = ffma(u1.z, n0, a1.z); a1.w = ffma(u1.w, n0, a1.w);
    a2.x = ffma(u2.x, n0, a2.x); a2.y = ffma(u2.y, n0, a2.y);
    a2.z = ffma(u2.z, n0, a2.z); a2.w = ffma(u2.w, n0, a2.w);
  }
  float4* op = (float4*)&out[(size_t)node * 96 + c12];
  op[0] = a0; op[1] = a1; op[2] = a2;
}

// ---------------- aggregation + BN (+tanh | +softmax) ----------------
template <int FO, bool SOFT>
__global__ __launch_bounds__(256) void k_agg(const float* __restrict__ XW,
                                             const int* __restrict__ offsets, const int* __restrict__ deg,
                                             const int2* __restrict__ adj,
                                             const float* __restrict__ dinv,
                                             const float* __restrict__ bnscale, const float* __restrict__ bnshift,
                                             int bnofs, float* __restrict__ out, int n) {
  constexpr int TPN = FO / 8;
  constexpr int NPB = 256 / TPN;
  int tid = threadIdx.x;
  int li = tid / TPN, c8 = (tid % TPN) * 8;
  int node = blockIdx.x * NPB + li;
  if (node >= n) return;

  float dv = dinv[node];
  float se = dv * dv;
  const float4* selfp = (const float4*)&XW[(size_t)node * FO + c8];
  float4 aL = selfp[0], aH = selfp[1];
  aL.x *= se; aL.y *= se; aL.z *= se; aL.w *= se;
  aH.x *= se; aH.y *= se; aH.z *= se; aH.w *= se;

  const int2* ap = adj + offsets[node];
  int cnt = deg[node] - 1;
  int e = 0;
#define EDGE_STEP(AA)                                                        \
  {                                                                          \
    float nm = __int_as_float((AA).y);                                       \
    const float4* q = (const float4*)&XW[(size_t)(AA).x * FO + c8];          \
    float4 v = q[0], w = q[1];                                               \
    aL.x = ffma(v.x, nm, aL.x); aL.y = ffma(v.y, nm, aL.y);                  \
    aL.z = ffma(v.z, nm, aL.z); aL.w = ffma(v.w, nm, aL.w);                  \
    aH.x = ffma(w.x, nm, aH.x); aH.y = ffma(w.y, nm, aH.y);                  \
    aH.z = ffma(w.z, nm, aH.z); aH.w = ffma(w.w, nm, aH.w);                  \
  }
  for (; e + 3 < cnt; e += 4) {
    int2 a0 = ap[e], a1 = ap[e + 1], a2 = ap[e + 2], a3 = ap[e + 3];
    EDGE_STEP(a0); EDGE_STEP(a1); EDGE_STEP(a2); EDGE_STEP(a3);
  }
  for (; e < cnt; e++) {
    int2 a0 = ap[e];
    EDGE_STEP(a0);
  }
#undef EDGE_STEP

  const float4 s4L = *(const float4*)&bnscale[bnofs + c8];
  const float4 s4H = *(const float4*)&bnscale[bnofs + c8 + 4];
  const float4 h4L = *(const float4*)&bnshift[bnofs + c8];
  const float4 h4H = *(const float4*)&bnshift[bnofs + c8 + 4];
  float r[8];
  r[0] = ffma(aL.x, s4L.x, h4L.x); r[1] = ffma(aL.y, s4L.y, h4L.y);
  r[2] = ffma(aL.z, s4L.z, h4L.z); r[3] = ffma(aL.w, s4L.w, h4L.w);
  r[4] = ffma(aH.x, s4H.x, h4H.x); r[5] = ffma(aH.y, s4H.y, h4H.y);
  r[6] = ffma(aH.z, s4H.z, h4H.z); r[7] = ffma(aH.w, s4H.w, h4H.w);

  float4 oL, oH;
  if constexpr (SOFT) {
    float mx = r[0];
#pragma unroll
    for (int i = 1; i < 8; i++) mx = fmaxf(mx, r[i]);
#pragma unroll
    for (int m = TPN / 2; m; m >>= 1) mx = fmaxf(mx, __shfl_xor(mx, m, TPN));
    float sm = 0.f;
#pragma unroll
    for (int i = 0; i < 8; i++) { r[i] = expf(r[i] - mx); sm += r[i]; }
#pragma unroll
    for (int m = TPN / 2; m; m >>= 1) sm += __shfl_xor(sm, m, TPN);
    float inv = 1.f / sm;
#pragma unroll
    for (int i = 0; i < 8; i++) r[i] *= inv;
  } else {
#pragma unroll
    for (int i = 0; i < 8; i++) r[i] = tanhf(r[i]);
  }
  oL = make_float4(r[0], r[1], r[2], r[3]);
  oH = make_float4(r[4], r[5], r[6], r[7]);
  float4* op = (float4*)&out[(size_t)node * FO + c8];
  op[0] = oL;
  op[1] = oH;
}

}  // namespace

extern "C" void kernel_launch(void* const* d_in, const int* in_sizes, int n_in,
                              void* d_out, int out_size, void* d_ws, size_t ws_size,
                              hipStream_t stream) {
  const float* x   = (const float*)d_in[0];
  const int*   ei  = (const int*)d_in[1];
  const float* cw1 = (const float*)d_in[2];
  const float* cb1 = (const float*)d_in[3];
  const float* cw2 = (const float*)d_in[4];
  const float* cb2 = (const float*)d_in[5];
  const float* cw3 = (const float*)d_in[6];
  const float* cb3 = (const float*)d_in[7];
  const float *gw[5], *gb[5], *bng[5], *bnb[5], *bnm[5], *bnv[5];
  for (int l = 0; l < 5; l++) {
    gw[l]  = (const float*)d_in[8 + 6 * l + 0];
    gb[l]  = (const float*)d_in[8 + 6 * l + 1];
    bng[l] = (const float*)d_in[8 + 6 * l + 2];
    bnb[l] = (const float*)d_in[8 + 6 * l + 3];
    bnm[l] = (const float*)d_in[8 + 6 * l + 4];
    bnv[l] = (const float*)d_in[8 + 6 * l + 5];
  }
  const int* srcp = ei;
  const int* dstp = ei + NE;

  char* w = (char*)d_ws;
  auto alloc = [&](size_t bytes) { char* p = w; w += (bytes + 255) & ~255ULL; return p; };
  int*   deg     = (int*)alloc((size_t)NN * 4);
  int*   offsets = (int*)alloc((size_t)NN * 4);
  int*   cursor  = (int*)alloc((size_t)NN * 4);
  int*   counter = (int*)alloc(256);
  float* dinv    = (float*)alloc((size_t)NN * 4);
  int2*  adj     = (int2*)alloc((size_t)NE * 8);
  float* w1p     = (float*)alloc(96 * 128 * 4);
  float* bnscale = (float*)alloc(400 * 4);
  float* bnshift = (float*)alloc(400 * 4);
  float* bufA    = (float*)alloc((size_t)NN * 128 * 4);
  float* bufB    = (float*)alloc((size_t)NN * 128 * 4);
  float* bufC    = (float*)alloc((size_t)NN * 128 * 4);

  int nb_n = (NN + 255) / 256;
  int nb_e = (NE + 255) / 256;
  k_init<<<nb_n, 256, 0, stream>>>(deg, counter, NN);
  k_count<<<nb_e, 256, 0, stream>>>(dstp, deg, NE);
  k_alloc<<<nb_n, 256, 0, stream>>>(deg, dinv, offsets, cursor, counter, NN);
  k_fill<<<nb_e, 256, 0, stream>>>(srcp, dstp, dinv, cursor, adj, NE);
  k_padw1<<<48, 256, 0, stream>>>(gw[0], w1p);
  {
    BNParams bp;
    for (int l = 0; l < 5; l++) {
      bp.bg[l] = bng[l]; bp.bv[l] = bnv[l]; bp.gb[l] = gb[l];
      bp.bm[l] = bnm[l]; bp.bb[l] = bnb[l];
    }
    k_bnprep<<<1, 512, 0, stream>>>(bp, bnscale, bnshift);
  }

  k_cnn<<<NN / 2, 256, 0, stream>>>(x, cw1, cb1, cw2, cb2, cw3, cb3, bufA);

  int gx2 = (NN + 127) / 128;   // 782
  // L1 (agg-first): AH = A@H (96 cols), then GEMM + fused BN+tanh
  k_agg96<<<(NN + 31) / 32, 256, 0, stream>>>(bufA, offsets, deg, adj, dinv, bufB, NN);
  k_gemm2<96, 128, 128, true><<<dim3(gx2, 1), 256, 0, stream>>>(bufB, w1p, bufC, NN, bnscale, bnshift, 0);
  // L2: [N,128]@[128,128] then agg
  k_gemm2<128, 128, 128><<<dim3(gx2, 1), 256, 0, stream>>>(bufC, gw[1], bufB, NN);
  k_agg<128, false><<<(NN + 15) / 16, 256, 0, stream>>>(bufB, offsets, deg, adj, dinv,
                                                        bnscale, bnshift, 128, bufA, NN);
  // L3: [N,128]@[128,64] then agg
  k_gemm2<128, 64, 64><<<dim3(gx2, 1), 256, 0, stream>>>(bufA, gw[2], bufB, NN);
  k_agg<64, false><<<(NN + 31) / 32, 256, 0, stream>>>(bufB, offsets, deg, adj, dinv,
                                                       bnscale, bnshift, 256, bufC, NN);
  // L4: [N,64]@[64,64] then agg
  k_gemm2<64, 64, 64><<<dim3(gx2, 1), 256, 0, stream>>>(bufC, gw[3], bufB, NN);
  k_agg<64, false><<<(NN + 31) / 32, 256, 0, stream>>>(bufB, offsets, deg, adj, dinv,
                                                       bnscale, bnshift, 320, bufA, NN);
  // L5: [N,64]@[64,16] then agg + BN + softmax -> d_out
  k_gemm16<<<(NN + 63) / 64, 256, 0, stream>>>(bufA, gw[4], bufB, NN);
  k_agg<16, true><<<(NN + 127) / 128, 256, 0, stream>>>(bufB, offsets, deg, adj, dinv,
                                                        bnscale, bnshift, 384, (float*)d_out, NN);
}